// Round 1
// baseline (542.169 us; speedup 1.0000x reference)
//
#include <hip/hip_runtime.h>

#define TT 2048
#define BATCH 256
#define LDC 132   // padded column stride for the Cayley solve
#define NCOL 130  // 128 matrix columns + 2 RHS columns

typedef float vfloat4 __attribute__((ext_vector_type(4)));

// ws float layout:
//   [0..127]   = Q[:,0]
//   [128..255] = Q[:,1]
//   [256..)    = d / h buffer, PACKED layout [t/4][B][t%4][2]
//                (32 B per (t4,b); RNN overwrites d with h in place)

// ---------------------------------------------------------------------------
// Kernel 1: input projection + transpose into packed layout.
// d[t4][b][m][2] = 0.1 * (wIn . u[b, 4*t4+m, :])
__global__ __launch_bounds__(256) void proj_kernel(
    const float* __restrict__ u, const float* __restrict__ wIn, float* __restrict__ ws)
{
    __shared__ float2 tile[64][33]; // [t_local][b_local], padded
    const int tid = threadIdx.x;
    const int tb = blockIdx.x & 31;  // t-tile 0..31
    const int bb = blockIdx.x >> 5;  // b-tile 0..7
    const int t0 = tb * 64;
    const int b0 = bb * 32;

    const float w00 = 0.1f * wIn[0], w01 = 0.1f * wIn[1], w02 = 0.1f * wIn[2];
    const float w10 = 0.1f * wIn[3], w11 = 0.1f * wIn[4], w12 = 0.1f * wIn[5];

    const int tl  = tid & 63;   // consecutive lanes -> consecutive t (coalesced u read)
    const int bl0 = tid >> 6;   // 0..3
#pragma unroll
    for (int s = 0; s < 8; ++s) {
        int bl = bl0 + s * 4;   // b_local 0..31
        const float* p = u + ((size_t)(b0 + bl) * TT + t0 + tl) * 3;
        float x = p[0], y = p[1], z = p[2];
        float2 dv;
        dv.x = fmaf(x, w00, fmaf(y, w01, z * w02));
        dv.y = fmaf(x, w10, fmaf(y, w11, z * w12));
        tile[tl][bl] = dv;
    }
    __syncthreads();

    float* d = ws + 256;
    const int bw  = tid & 31;   // consecutive lanes -> consecutive b
    const int tg0 = tid >> 5;   // 0..7 (t4 within tile, two passes -> 16 t4 groups)
#pragma unroll
    for (int s = 0; s < 2; ++s) {
        int t4l = tg0 + s * 8;  // local t4: 0..15
        float2 a0 = tile[t4l * 4 + 0][bw];
        float2 a1 = tile[t4l * 4 + 1][bw];
        float2 a2 = tile[t4l * 4 + 2][bw];
        float2 a3 = tile[t4l * 4 + 3][bw];
        float* p = d + ((size_t)((t0 >> 2) + t4l) * BATCH + (b0 + bw)) * 8;
        vfloat4 w0, w1;
        w0.x = a0.x; w0.y = a0.y; w0.z = a1.x; w0.w = a1.y;
        w1.x = a2.x; w1.y = a2.y; w1.z = a3.x; w1.w = a3.y;
        *(vfloat4*)p       = w0;
        *(vfloat4*)(p + 4) = w1;
    }
}

// ---------------------------------------------------------------------------
// Kernel 2: block 0 = Cayley solve (2 columns of Q), blocks 1..4 = RNN chains
// (64 chains per block on 4 separate CUs; waves 1-3 of each RNN block warm L2).
__global__ __launch_bounds__(256) void ge_rnn_kernel(
    const float* __restrict__ matB, const float* __restrict__ wRec,
    float* __restrict__ ws)
{
    if (blockIdx.x == 0) {
        // ---- Solve (I+A) v_c = e_c (c=0,1), then q_c = (I-A) v_c ----
        __shared__ __align__(16) float Mc[NCOL * LDC]; // column-major: Mc[j*LDC + i]
        __shared__ float vb[256];
        const int tid = threadIdx.x;

        for (int e = tid; e < 128 * 128; e += 256) {
            int i = e >> 7, j = e & 127;
            float a = matB[i * 128 + j] - matB[j * 128 + i]; // A[i][j]
            Mc[j * LDC + i] = a + ((i == j) ? 1.0f : 0.0f);
        }
        for (int i = tid; i < 128; i += 256) {
            Mc[128 * LDC + i] = (i == 0) ? 1.0f : 0.0f; // RHS e0
            Mc[129 * LDC + i] = (i == 1) ? 1.0f : 0.0f; // RHS e1
        }
        __syncthreads();

        // Right-looking elimination: ONE barrier per pivot.
        // Column j update: M[:,j] -= M[:,k] * (M[k][j]/M[k][k]); per-thread divide,
        // column-k reads are same-address broadcasts (conflict-free).
        for (int k = 0; k < 127; ++k) {
            int j = tid;
            if (j > k && j < NCOL) {
                float scale = Mc[j * LDC + k] / Mc[k * LDC + k];
                int i = k + 1;
                int iv = (i + 3) & ~3;
                if (iv > 128) iv = 128;
                for (; i < iv; ++i)
                    Mc[j * LDC + i] = fmaf(-Mc[k * LDC + i], scale, Mc[j * LDC + i]);
                for (; i < 128; i += 4) {
                    float4 m = *(float4*)&Mc[j * LDC + i];
                    float4 f = *(const float4*)&Mc[k * LDC + i];
                    m.x = fmaf(-f.x, scale, m.x);
                    m.y = fmaf(-f.y, scale, m.y);
                    m.z = fmaf(-f.z, scale, m.z);
                    m.w = fmaf(-f.w, scale, m.w);
                    *(float4*)&Mc[j * LDC + i] = m;
                }
            }
            __syncthreads();
        }

        // Barrier-free back-substitution on wave 0: lane l owns rows l and l+64,
        // two RHS in registers; v_k broadcast via __shfl.
        if (tid < 64) {
            const int l = tid;
            float r0 = Mc[128 * LDC + l],      s0 = Mc[129 * LDC + l];
            float r1 = Mc[128 * LDC + l + 64], s1 = Mc[129 * LDC + l + 64];
            for (int k = 127; k >= 0; --k) {
                float Ukk = Mc[k * LDC + k];
                float c0 = (k >= 64) ? r1 : r0;
                float c1 = (k >= 64) ? s1 : s0;
                float v0 = __shfl(c0, k & 63) / Ukk;
                float v1 = __shfl(c1, k & 63) / Ukk;
                if (l == (k & 63)) { vb[k] = v0; vb[128 + k] = v1; }
                float ul = Mc[k * LDC + l];
                float uh = Mc[k * LDC + l + 64];
                if (l < k)      { r0 = fmaf(-ul, v0, r0); s0 = fmaf(-ul, v1, s0); }
                if (l + 64 < k) { r1 = fmaf(-uh, v0, r1); s1 = fmaf(-uh, v1, s1); }
            }
        }
        __syncthreads();

        // q_c = v_c - A v_c
        if (tid < 128) {
            int i = tid;
            float q0 = vb[i], q1 = vb[128 + i];
            for (int j = 0; j < 128; ++j) {
                float aij = matB[i * 128 + j] - matB[j * 128 + i];
                q0 = fmaf(-aij, vb[j],       q0);
                q1 = fmaf(-aij, vb[128 + j], q1);
            }
            ws[i]       = q0;
            ws[128 + i] = q1;
        }
    } else {
        // ---- leaky RNN: 64 chains on wave 0; waves 1-3 prefetch d into L2 ----
        const int lane = threadIdx.x;
        if (lane >= 64) {
            // L2-warming prefetch of this block's 1 MB d-region (values discarded).
            const int pid = lane - 64;  // 0..191
            const float* dd = ws + 256;
            const size_t boff = (size_t)(blockIdx.x - 1) * 64 * 8;
            float acc = 0.f;
            for (int c = pid; c < 512 * 128; c += 192) {
                int t4 = c >> 7, part = c & 127;
                vfloat4 v = *(const vfloat4*)(dd + (size_t)t4 * (BATCH * 8) + boff + part * 4);
                acc += v.x + v.y + v.z + v.w;
            }
            asm volatile("" :: "v"(acc)); // keep loads live (no DCE)
            return;
        }
        const int b = (blockIdx.x - 1) * 64 + lane;
        float* base = ws + 256 + (size_t)b * 8;   // + t4 * 2048 floats
        const float a00 = 0.1f * wRec[0], a01 = 0.1f * wRec[1];
        const float a10 = 0.1f * wRec[2], a11 = 0.1f * wRec[3];
        float y0 = 0.f, y1 = 0.f;

        vfloat4 A[16], Bv[16];  // two 32-step bodies (8 t4-groups x 2 dwordx4 each)

#define RNN_STEP(d0, d1) do {                                   \
        float rr0 = fmaxf(y0, 0.f), rr1 = fmaxf(y1, 0.f);       \
        float p0 = fmaf(0.9f, y0, (d0));                        \
        float p1 = fmaf(0.9f, y1, (d1));                        \
        y0 = fmaf(rr1, a01, fmaf(rr0, a00, p0));                \
        y1 = fmaf(rr1, a11, fmaf(rr0, a10, p1));                \
        (d0) = y0; (d1) = y1; } while (0)

        auto LOAD = [&](vfloat4* buf, int g) {
#pragma unroll
            for (int k = 0; k < 8; ++k) {
                const float* p = base + (size_t)(g * 8 + k) * (BATCH * 8);
                buf[2 * k]     = *(const vfloat4*)p;
                buf[2 * k + 1] = *(const vfloat4*)(p + 4);
            }
        };
        auto CSTORE = [&](vfloat4* buf, int g) {
#pragma unroll
            for (int k = 0; k < 8; ++k) {
                vfloat4 v0 = buf[2 * k], v1 = buf[2 * k + 1];
                RNN_STEP(v0.x, v0.y);
                RNN_STEP(v0.z, v0.w);
                RNN_STEP(v1.x, v1.y);
                RNN_STEP(v1.z, v1.w);
                float* p = base + (size_t)(g * 8 + k) * (BATCH * 8);
                *(vfloat4*)p       = v0;
                *(vfloat4*)(p + 4) = v1;
            }
        };

        // depth-2 ping-pong over 64 bodies of 32 steps each
        LOAD(A, 0);
        for (int g = 0; g < 62; g += 2) {
            LOAD(Bv, g + 1);
            CSTORE(A, g);
            LOAD(A, g + 2);
            CSTORE(Bv, g + 1);
        }
        LOAD(Bv, 63);
        CSTORE(A, 62);
        CSTORE(Bv, 63);
#undef RNN_STEP
    }
}

// ---------------------------------------------------------------------------
// Kernel 3: out[b,t,:] = h0 * Q[:,0] + h1 * Q[:,1]   (h in packed layout)
__global__ __launch_bounds__(256) void out_kernel(
    const float* __restrict__ ws, float* __restrict__ out)
{
    const int tid = threadIdx.x;
    const int jg  = tid & 31;   // 32 lanes cover the 128 output features (float4 each)
    const int sub = tid >> 5;   // 8 (b,t) pairs per block-iteration
    float4 qa = *(const float4*)(ws + jg * 4);
    float4 qb = *(const float4*)(ws + 128 + jg * 4);
    const float* h = ws + 256;  // packed [t4][B][m][2]
    const int ngroups = BATCH * (TT / 8); // 65536: g = b*256 + tchunk
    for (int g = blockIdx.x; g < ngroups; g += gridDim.x) {
        int b = g >> 8;
        int t = (g & 255) * 8 + sub;
        const float* hp = h + ((size_t)(t >> 2) * BATCH + b) * 8 + (t & 3) * 2;
        float2 hv = *(const float2*)hp;
        vfloat4 o;
        o.x = fmaf(hv.x, qa.x, hv.y * qb.x);
        o.y = fmaf(hv.x, qa.y, hv.y * qb.y);
        o.z = fmaf(hv.x, qa.z, hv.y * qb.z);
        o.w = fmaf(hv.x, qa.w, hv.y * qb.w);
        __builtin_nontemporal_store(o, (vfloat4*)(out + ((size_t)b * TT + t) * 128 + jg * 4));
    }
}

extern "C" void kernel_launch(void* const* d_in, const int* in_sizes, int n_in,
                              void* d_out, int out_size, void* d_ws, size_t ws_size,
                              hipStream_t stream) {
    const float* u    = (const float*)d_in[0];
    const float* matB = (const float*)d_in[1];
    const float* wIn  = (const float*)d_in[2];
    const float* wRec = (const float*)d_in[3];
    float* out = (float*)d_out;
    float* ws  = (float*)d_ws;

    hipLaunchKernelGGL(proj_kernel,   dim3(256),  dim3(256), 0, stream, u, wIn, ws);
    hipLaunchKernelGGL(ge_rnn_kernel, dim3(5),    dim3(256), 0, stream, matB, wRec, ws);
    hipLaunchKernelGGL(out_kernel,    dim3(8192), dim3(256), 0, stream, ws, out);
}

// Round 2
// 518.455 us; speedup vs baseline: 1.0457x; 1.0457x over previous
//
#include <hip/hip_runtime.h>

#define TT 2048
#define BATCH 256
#define NCOL 130  // 128 matrix columns + 2 RHS columns

typedef float vfloat4 __attribute__((ext_vector_type(4)));

// ws float layout:
//   [0..127]   = Q[:,0]
//   [128..255] = Q[:,1]
//   [256..)    = d / h buffer, PACKED layout [t/4][B][t%4][2]
//                (32 B per (t4,b); RNN overwrites d with h in place)

// Cayley LDS addressing: column-major, LDC=128, float4-granule XOR swizzle.
// bank(lane j, elem i) = (4*((i/4)^(j&7)) + i%4) % 32 -> the 8 lane-groups
// (j mod 8) land on 8 distinct 4-bank spans => conflict-free b128 column access.
// Same-column reads (pivot col k) remain same-address broadcasts.
#define MCI(j, i) ((j) * 128 + (((((i) >> 2) ^ ((j) & 7)) << 2) | ((i) & 3)))

// ---------------------------------------------------------------------------
// Kernel 1: input projection + transpose into packed layout.
__global__ __launch_bounds__(256) void proj_kernel(
    const float* __restrict__ u, const float* __restrict__ wIn, float* __restrict__ ws)
{
    __shared__ float2 tile[64][33]; // [t_local][b_local], padded
    const int tid = threadIdx.x;
    const int tb = blockIdx.x & 31;  // t-tile 0..31
    const int bb = blockIdx.x >> 5;  // b-tile 0..7
    const int t0 = tb * 64;
    const int b0 = bb * 32;

    const float w00 = 0.1f * wIn[0], w01 = 0.1f * wIn[1], w02 = 0.1f * wIn[2];
    const float w10 = 0.1f * wIn[3], w11 = 0.1f * wIn[4], w12 = 0.1f * wIn[5];

    const int tl  = tid & 63;   // consecutive lanes -> consecutive t (coalesced u read)
    const int bl0 = tid >> 6;   // 0..3
#pragma unroll
    for (int s = 0; s < 8; ++s) {
        int bl = bl0 + s * 4;   // b_local 0..31
        const float* p = u + ((size_t)(b0 + bl) * TT + t0 + tl) * 3;
        float x = p[0], y = p[1], z = p[2];
        float2 dv;
        dv.x = fmaf(x, w00, fmaf(y, w01, z * w02));
        dv.y = fmaf(x, w10, fmaf(y, w11, z * w12));
        tile[tl][bl] = dv;
    }
    __syncthreads();

    float* d = ws + 256;
    const int bw  = tid & 31;   // consecutive lanes -> consecutive b
    const int tg0 = tid >> 5;   // 0..7
#pragma unroll
    for (int s = 0; s < 2; ++s) {
        int t4l = tg0 + s * 8;  // local t4: 0..15
        float2 a0 = tile[t4l * 4 + 0][bw];
        float2 a1 = tile[t4l * 4 + 1][bw];
        float2 a2 = tile[t4l * 4 + 2][bw];
        float2 a3 = tile[t4l * 4 + 3][bw];
        float* p = d + ((size_t)((t0 >> 2) + t4l) * BATCH + (b0 + bw)) * 8;
        vfloat4 w0, w1;
        w0.x = a0.x; w0.y = a0.y; w0.z = a1.x; w0.w = a1.y;
        w1.x = a2.x; w1.y = a2.y; w1.z = a3.x; w1.w = a3.y;
        *(vfloat4*)p       = w0;
        *(vfloat4*)(p + 4) = w1;
    }
}

// ---------------------------------------------------------------------------
// Kernel 2: block 0 = Cayley solve (2 columns of Q), blocks 1..4 = RNN chains
// (64 chains on wave 0 of each RNN block; buffers in NAMED registers — no
// arrays, no lambdas: pointer-parameterized lambdas spilled to scratch in R1).
__global__ __launch_bounds__(256, 1) void ge_rnn_kernel(
    const float* __restrict__ matB, const float* __restrict__ wRec,
    float* __restrict__ ws)
{
    if (blockIdx.x == 0) {
        // ---- Solve (I+A) v_c = e_c (c=0,1), then q_c = (I-A) v_c ----
        __shared__ __align__(16) float Mc[NCOL * 128]; // swizzled column-major
        __shared__ float vb[256];
        const int tid = threadIdx.x;

        for (int e = tid; e < 128 * 128; e += 256) {
            int i = e >> 7, j = e & 127;
            float a = matB[i * 128 + j] - matB[j * 128 + i]; // A[i][j]
            Mc[MCI(j, i)] = a + ((i == j) ? 1.0f : 0.0f);
        }
        for (int i = tid; i < 128; i += 256) {
            Mc[MCI(128, i)] = (i == 0) ? 1.0f : 0.0f; // RHS e0
            Mc[MCI(129, i)] = (i == 1) ? 1.0f : 0.0f; // RHS e1
        }
        __syncthreads();

        // Right-looking elimination: ONE barrier per pivot, conflict-free b128.
        for (int k = 0; k < 127; ++k) {
            int j = tid;
            if (j > k && j < NCOL) {
                float scale = Mc[MCI(j, k)] / Mc[MCI(k, k)];
                int i = k + 1;
                int iv = (i + 3) & ~3;
                if (iv > 128) iv = 128;
                for (; i < iv; ++i)
                    Mc[MCI(j, i)] = fmaf(-Mc[MCI(k, i)], scale, Mc[MCI(j, i)]);
                for (; i < 128; i += 4) {
                    float4 m = *(float4*)&Mc[MCI(j, i)];
                    float4 f = *(const float4*)&Mc[MCI(k, i)];
                    m.x = fmaf(-f.x, scale, m.x);
                    m.y = fmaf(-f.y, scale, m.y);
                    m.z = fmaf(-f.z, scale, m.z);
                    m.w = fmaf(-f.w, scale, m.w);
                    *(float4*)&Mc[MCI(j, i)] = m;
                }
            }
            __syncthreads();
        }

        // Barrier-free back-substitution on wave 0: lane l owns rows l and l+64.
        if (tid < 64) {
            const int l = tid;
            float r0 = Mc[MCI(128, l)],      s0 = Mc[MCI(129, l)];
            float r1 = Mc[MCI(128, l + 64)], s1 = Mc[MCI(129, l + 64)];
            for (int k = 127; k >= 0; --k) {
                float Ukk = Mc[MCI(k, k)];
                float c0 = (k >= 64) ? r1 : r0;
                float c1 = (k >= 64) ? s1 : s0;
                float v0 = __shfl(c0, k & 63) / Ukk;
                float v1 = __shfl(c1, k & 63) / Ukk;
                if (l == (k & 63)) { vb[k] = v0; vb[128 + k] = v1; }
                float ul = Mc[MCI(k, l)];
                float uh = Mc[MCI(k, l + 64)];
                if (l < k)      { r0 = fmaf(-ul, v0, r0); s0 = fmaf(-ul, v1, s0); }
                if (l + 64 < k) { r1 = fmaf(-uh, v0, r1); s1 = fmaf(-uh, v1, s1); }
            }
        }
        __syncthreads();

        // q_c = v_c - A v_c
        if (tid < 128) {
            int i = tid;
            float q0 = vb[i], q1 = vb[128 + i];
            for (int j = 0; j < 128; ++j) {
                float aij = matB[i * 128 + j] - matB[j * 128 + i];
                q0 = fmaf(-aij, vb[j],       q0);
                q1 = fmaf(-aij, vb[128 + j], q1);
            }
            ws[i]       = q0;
            ws[128 + i] = q1;
        }
    } else {
        // ---- leaky RNN: 64 chains, wave 0 only ----
        const int lane = threadIdx.x;
        if (lane >= 64) return;
        const int b = (blockIdx.x - 1) * 64 + lane;
        float* base = ws + 256 + (size_t)b * 8;   // + t4 * 2048 floats
        const float a00 = 0.1f * wRec[0], a01 = 0.1f * wRec[1];
        const float a10 = 0.1f * wRec[2], a11 = 0.1f * wRec[3];
        float y0 = 0.f, y1 = 0.f;

        // two 32-step bodies in NAMED registers (16 vfloat4 each)
        vfloat4 A0, A1, A2, A3, A4, A5, A6, A7, A8, A9, A10, A11, A12, A13, A14, A15;
        vfloat4 B0, B1, B2, B3, B4, B5, B6, B7, B8, B9, B10, B11, B12, B13, B14, B15;

#define RNN_STEP(d0, d1) do {                                   \
        float rr0 = fmaxf(y0, 0.f), rr1 = fmaxf(y1, 0.f);       \
        float p0 = fmaf(0.9f, y0, (d0));                        \
        float p1 = fmaf(0.9f, y1, (d1));                        \
        y0 = fmaf(rr1, a01, fmaf(rr0, a00, p0));                \
        y1 = fmaf(rr1, a11, fmaf(rr0, a10, p1));                \
        (d0) = y0; (d1) = y1; } while (0)

#define LOAD16(V, g) do { \
        const float* _p = base + (size_t)(g) * (8 * BATCH * 8); \
        V##0  = *(const vfloat4*)(_p + 0 * 2048); V##1  = *(const vfloat4*)(_p + 0 * 2048 + 4); \
        V##2  = *(const vfloat4*)(_p + 1 * 2048); V##3  = *(const vfloat4*)(_p + 1 * 2048 + 4); \
        V##4  = *(const vfloat4*)(_p + 2 * 2048); V##5  = *(const vfloat4*)(_p + 2 * 2048 + 4); \
        V##6  = *(const vfloat4*)(_p + 3 * 2048); V##7  = *(const vfloat4*)(_p + 3 * 2048 + 4); \
        V##8  = *(const vfloat4*)(_p + 4 * 2048); V##9  = *(const vfloat4*)(_p + 4 * 2048 + 4); \
        V##10 = *(const vfloat4*)(_p + 5 * 2048); V##11 = *(const vfloat4*)(_p + 5 * 2048 + 4); \
        V##12 = *(const vfloat4*)(_p + 6 * 2048); V##13 = *(const vfloat4*)(_p + 6 * 2048 + 4); \
        V##14 = *(const vfloat4*)(_p + 7 * 2048); V##15 = *(const vfloat4*)(_p + 7 * 2048 + 4); \
    } while (0)

#define PAIR(Va, Vb, q, off) do { \
        RNN_STEP(Va.x, Va.y); RNN_STEP(Va.z, Va.w); \
        RNN_STEP(Vb.x, Vb.y); RNN_STEP(Vb.z, Vb.w); \
        *(vfloat4*)((q) + (off)) = Va; *(vfloat4*)((q) + (off) + 4) = Vb; \
    } while (0)

#define CSTORE16(V, g) do { \
        float* _q = base + (size_t)(g) * (8 * BATCH * 8); \
        PAIR(V##0,  V##1,  _q, 0 * 2048); \
        PAIR(V##2,  V##3,  _q, 1 * 2048); \
        PAIR(V##4,  V##5,  _q, 2 * 2048); \
        PAIR(V##6,  V##7,  _q, 3 * 2048); \
        PAIR(V##8,  V##9,  _q, 4 * 2048); \
        PAIR(V##10, V##11, _q, 5 * 2048); \
        PAIR(V##12, V##13, _q, 6 * 2048); \
        PAIR(V##14, V##15, _q, 7 * 2048); \
    } while (0)

        // depth-2 ping-pong over 64 bodies of 32 steps each
        LOAD16(A, 0);
        for (int g = 0; g <= 60; g += 2) {
            LOAD16(B, g + 1);
            CSTORE16(A, g);
            LOAD16(A, g + 2);
            CSTORE16(B, g + 1);
        }
        LOAD16(B, 63);
        CSTORE16(A, 62);
        CSTORE16(B, 63);
#undef RNN_STEP
#undef LOAD16
#undef PAIR
#undef CSTORE16
    }
}

// ---------------------------------------------------------------------------
// Kernel 3: out[b,t,:] = h0 * Q[:,0] + h1 * Q[:,1]   (h in packed layout)
// Each block owns one b and 64 consecutive t: 32 KB contiguous stores/block.
__global__ __launch_bounds__(256) void out_kernel(
    const float* __restrict__ ws, float* __restrict__ out)
{
    const int tid = threadIdx.x;
    const int jg  = tid & 31;   // 32 lanes cover the 128 output features (float4 each)
    const int sub = tid >> 5;   // 8 t-values per iteration
    float4 qa = *(const float4*)(ws + jg * 4);
    float4 qb = *(const float4*)(ws + 128 + jg * 4);
    const float* h = ws + 256;  // packed [t4][B][m][2]

    const int b  = blockIdx.x >> 5;         // 0..255
    const int t0 = (blockIdx.x & 31) * 64;  // 64 consecutive t per block

    // prefetch all 8 h-values up front (registers, compile-time indices)
    float2 hv0, hv1, hv2, hv3, hv4, hv5, hv6, hv7;
#define HLOAD(R, i) do { int t = t0 + (i) * 8 + sub; \
        R = *(const float2*)(h + ((size_t)(t >> 2) * BATCH + b) * 8 + (t & 3) * 2); } while (0)
    HLOAD(hv0, 0); HLOAD(hv1, 1); HLOAD(hv2, 2); HLOAD(hv3, 3);
    HLOAD(hv4, 4); HLOAD(hv5, 5); HLOAD(hv6, 6); HLOAD(hv7, 7);
#undef HLOAD

#define OSTORE(R, i) do { int t = t0 + (i) * 8 + sub; \
        vfloat4 o; \
        o.x = fmaf(R.x, qa.x, R.y * qb.x); \
        o.y = fmaf(R.x, qa.y, R.y * qb.y); \
        o.z = fmaf(R.x, qa.z, R.y * qb.z); \
        o.w = fmaf(R.x, qa.w, R.y * qb.w); \
        __builtin_nontemporal_store(o, (vfloat4*)(out + ((size_t)b * TT + t) * 128 + jg * 4)); } while (0)
    OSTORE(hv0, 0); OSTORE(hv1, 1); OSTORE(hv2, 2); OSTORE(hv3, 3);
    OSTORE(hv4, 4); OSTORE(hv5, 5); OSTORE(hv6, 6); OSTORE(hv7, 7);
#undef OSTORE
}

extern "C" void kernel_launch(void* const* d_in, const int* in_sizes, int n_in,
                              void* d_out, int out_size, void* d_ws, size_t ws_size,
                              hipStream_t stream) {
    const float* u    = (const float*)d_in[0];
    const float* matB = (const float*)d_in[1];
    const float* wIn  = (const float*)d_in[2];
    const float* wRec = (const float*)d_in[3];
    float* out = (float*)d_out;
    float* ws  = (float*)d_ws;

    hipLaunchKernelGGL(proj_kernel,   dim3(256),  dim3(256), 0, stream, u, wIn, ws);
    hipLaunchKernelGGL(ge_rnn_kernel, dim3(5),    dim3(256), 0, stream, matB, wRec, ws);
    hipLaunchKernelGGL(out_kernel,    dim3(8192), dim3(256), 0, stream, ws, out);
}